// Round 1
// baseline (1303.140 us; speedup 1.0000x reference)
//
#include <hip/hip_runtime.h>

// Problem constants (match reference)
#define N_L   90
#define N_B   20
#define N_MU  46
#define N_LF  51
#define N_CELLS (N_L * N_B * N_MU)      // 82800
#define N_OUTK  (N_LF - N_MU + 1)       // 6
#define N_PART  20000000

// dx computed exactly as numpy float32: (maxs-mins) exact, divided by (ns-1)
// 180.f/89.f, 24.f/19.f, 9.f/45.f — compile-time IEEE f32 constants.

__global__ void zero_hist_kernel(float* __restrict__ hist) {
    int i = blockIdx.x * blockDim.x + threadIdx.x;
    if (i < N_CELLS) hist[i] = 0.0f;
}

__device__ __forceinline__ void bin_particle(float x, float y, float z, float m,
                                             float* __restrict__ hist) {
    // IEEE f32 division to match JAX exactly; rintf = round-half-even = jnp.round
    float f0 = rintf((x - (-90.0f)) / (180.0f / 89.0f));
    float f1 = rintf((y - (-12.0f)) / (24.0f / 19.0f));
    float f2 = rintf((z - 7.0f)    / (9.0f / 45.0f));
    int i0 = (int)f0;
    int i1 = (int)f1;
    int i2 = (int)f2;
    bool valid = (i0 >= 0) & (i0 < N_L) & (i1 >= 0) & (i1 < N_B) &
                 (i2 >= 0) & (i2 < N_MU);
    if (valid) {
        int flat = (i0 * N_B + i1) * N_MU + i2;
        // HW global_atomic_add_f32 (device scope) — NOT a CAS loop
        unsafeAtomicAdd(&hist[flat], m);
    }
}

__global__ __launch_bounds__(256) void hist_kernel(
        const float* __restrict__ lbm,
        const float* __restrict__ masses,
        float* __restrict__ hist) {
    const float4* __restrict__ lbm4 = (const float4*)lbm;
    const float4* __restrict__ m4   = (const float4*)masses;
    int q = blockIdx.x * blockDim.x + threadIdx.x;   // one quad of particles
    if (q >= N_PART / 4) return;
    // 4 particles = 12 floats = 3 coalesced float4 loads
    float4 a = lbm4[3 * q + 0];
    float4 b = lbm4[3 * q + 1];
    float4 c = lbm4[3 * q + 2];
    float4 m = m4[q];
    bin_particle(a.x, a.y, a.z, m.x, hist);
    bin_particle(a.w, b.x, b.y, m.y, hist);
    bin_particle(b.z, b.w, c.x, m.z, hist);
    bin_particle(c.y, c.z, c.w, m.w, hist);
}

__global__ __launch_bounds__(256) void conv_kernel(
        const float* __restrict__ hist,
        const float* __restrict__ lf,
        float* __restrict__ out) {
    __shared__ float s_lf[N_LF];
    int t = threadIdx.x;
    if (t < N_LF) s_lf[t] = lf[t];
    __syncthreads();
    int cell = blockIdx.x * blockDim.x + t;          // (l,b) pair index, 1800 total
    if (cell < N_L * N_B) {
        float acc[N_OUTK];
        #pragma unroll
        for (int k = 0; k < N_OUTK; ++k) acc[k] = 0.0f;
        #pragma unroll 2
        for (int i = 0; i < N_MU; ++i) {
            float h = hist[cell * N_MU + i];
            #pragma unroll
            for (int k = 0; k < N_OUTK; ++k)
                acc[k] += h * s_lf[k + (N_MU - 1) - i];
        }
        #pragma unroll
        for (int k = 0; k < N_OUTK; ++k)
            out[cell * N_OUTK + k] = acc[k];
    }
}

extern "C" void kernel_launch(void* const* d_in, const int* in_sizes, int n_in,
                              void* d_out, int out_size, void* d_ws, size_t ws_size,
                              hipStream_t stream) {
    const float* lbm    = (const float*)d_in[0];   // [20e6, 3] f32
    const float* masses = (const float*)d_in[1];   // [20e6]    f32
    const float* lf     = (const float*)d_in[2];   // [51]      f32
    float* out  = (float*)d_out;                   // [90,20,6] f32
    float* hist = (float*)d_ws;                    // 82800 f32 scratch

    // 1. zero histogram (ws is poisoned 0xAA every call)
    zero_hist_kernel<<<(N_CELLS + 255) / 256, 256, 0, stream>>>(hist);

    // 2. histogram: one thread per 4 particles
    int quads = N_PART / 4;                        // 5,000,000
    hist_kernel<<<(quads + 255) / 256, 256, 0, stream>>>(lbm, masses, hist);

    // 3. conv over mu: 1800 (l,b) cells, 6 outputs each
    conv_kernel<<<(N_L * N_B + 255) / 256, 256, 0, stream>>>(hist, lf, out);
}

// Round 2
// 446.473 us; speedup vs baseline: 2.9187x; 2.9187x over previous
//
#include <hip/hip_runtime.h>

// Problem constants (match reference)
#define N_L   90
#define N_B   20
#define N_MU  46
#define N_LF  51
#define N_CELLS (N_L * N_B * N_MU)      // 82800
#define N_OUTK  (N_LF - N_MU + 1)       // 6
#define N_PART  20000000
#define QUADS   (N_PART / 4)            // 5,000,000

// LDS-privatization config: split l-dimension into 3 ranges of 30
#define R_SPLIT 3
#define L_PER   (N_L / R_SPLIT)         // 30
#define SLICE   (L_PER * N_B * N_MU)    // 27600 floats = 110,400 B LDS
#define C_MAX   85                      // chunks -> 255 blocks = 1 residency round
#define HIST_BLOCK 1024

// ---------------- shared binning math (must match jnp bit-for-bit) ----------
// dx = (maxs-mins)/(ns-1) in f32: 180/89, 24/19, 9/45 — IEEE f32 constants.
// rintf = round-half-even = jnp.round. IEEE division, no fast-math rewrites.

__device__ __forceinline__ void compute_idx(float x, float y, float z,
                                            int& i0, int& i1, int& i2) {
    i0 = (int)rintf((x + 90.0f) / (180.0f / 89.0f));
    i1 = (int)rintf((y + 12.0f) / (24.0f / 19.0f));
    i2 = (int)rintf((z - 7.0f)  / (9.0f / 45.0f));
}

// ---------------- main path: LDS-privatized histogram -----------------------

__device__ __forceinline__ void bin_lds(float x, float y, float z, float m,
                                        int l_lo, float* __restrict__ s_hist) {
    int i0, i1, i2;
    compute_idx(x, y, z, i0, i1, i2);
    bool ok = (i0 >= l_lo) & (i0 < l_lo + L_PER) &
              (i1 >= 0) & (i1 < N_B) & (i2 >= 0) & (i2 < N_MU);
    if (ok) {
        atomicAdd(&s_hist[((i0 - l_lo) * N_B + i1) * N_MU + i2], m);  // ds_add_f32
    }
}

__global__ __launch_bounds__(HIST_BLOCK) void hist_lds_kernel(
        const float4* __restrict__ lbm4,
        const float4* __restrict__ m4,
        float* __restrict__ slices,          // [R_SPLIT * C][SLICE]
        int C, int quads_per_chunk) {
    __shared__ float s_hist[SLICE];
    // bid = chunk*R + range: the R siblings of a chunk are dispatch-adjacent,
    // so the chunk's particle data is L3-hot for siblings 2 and 3.
    int c = blockIdx.x / R_SPLIT;
    int r = blockIdx.x % R_SPLIT;
    int l_lo = r * L_PER;

    for (int i = threadIdx.x; i < SLICE; i += HIST_BLOCK) s_hist[i] = 0.0f;
    __syncthreads();

    int q0 = c * quads_per_chunk;
    int q1 = q0 + quads_per_chunk;
    if (q1 > QUADS) q1 = QUADS;
    for (int q = q0 + threadIdx.x; q < q1; q += HIST_BLOCK) {
        float4 a = lbm4[3 * q + 0];
        float4 b = lbm4[3 * q + 1];
        float4 d = lbm4[3 * q + 2];
        float4 m = m4[q];
        bin_lds(a.x, a.y, a.z, m.x, l_lo, s_hist);
        bin_lds(a.w, b.x, b.y, m.y, l_lo, s_hist);
        bin_lds(b.z, b.w, d.x, m.z, l_lo, s_hist);
        bin_lds(d.y, d.z, d.w, m.w, l_lo, s_hist);
    }
    __syncthreads();

    // flush LDS slice to this block's PRIVATE global copy — plain coalesced
    // stores, zero atomics.
    float* dst = slices + (size_t)(r * C + c) * SLICE;
    for (int i = threadIdx.x; i < SLICE; i += HIST_BLOCK) dst[i] = s_hist[i];
}

__global__ __launch_bounds__(256) void reduce_kernel(
        const float* __restrict__ slices, float* __restrict__ hist, int C) {
    int j = blockIdx.x * 256 + threadIdx.x;   // global cell id
    if (j >= N_CELLS) return;
    int r = j / SLICE;
    int off = j - r * SLICE;
    const float* p = slices + (size_t)(r * C) * SLICE + off;
    float s = 0.0f;
    for (int c = 0; c < C; ++c) s += p[(size_t)c * SLICE];
    hist[j] = s;
}

// ---------------- fallback path (round-1): global atomics -------------------

__global__ void zero_hist_kernel(float* __restrict__ hist) {
    int i = blockIdx.x * blockDim.x + threadIdx.x;
    if (i < N_CELLS) hist[i] = 0.0f;
}

__device__ __forceinline__ void bin_global(float x, float y, float z, float m,
                                           float* __restrict__ hist) {
    int i0, i1, i2;
    compute_idx(x, y, z, i0, i1, i2);
    bool ok = (i0 >= 0) & (i0 < N_L) & (i1 >= 0) & (i1 < N_B) &
              (i2 >= 0) & (i2 < N_MU);
    if (ok) unsafeAtomicAdd(&hist[(i0 * N_B + i1) * N_MU + i2], m);
}

__global__ __launch_bounds__(256) void hist_atomic_kernel(
        const float4* __restrict__ lbm4,
        const float4* __restrict__ m4,
        float* __restrict__ hist) {
    int q = blockIdx.x * blockDim.x + threadIdx.x;
    if (q >= QUADS) return;
    float4 a = lbm4[3 * q + 0];
    float4 b = lbm4[3 * q + 1];
    float4 d = lbm4[3 * q + 2];
    float4 m = m4[q];
    bin_global(a.x, a.y, a.z, m.x, hist);
    bin_global(a.w, b.x, b.y, m.y, hist);
    bin_global(b.z, b.w, d.x, m.z, hist);
    bin_global(d.y, d.z, d.w, m.w, hist);
}

// ---------------- conv epilogue ---------------------------------------------

__global__ __launch_bounds__(256) void conv_kernel(
        const float* __restrict__ hist,
        const float* __restrict__ lf,
        float* __restrict__ out) {
    __shared__ float s_lf[N_LF];
    int t = threadIdx.x;
    if (t < N_LF) s_lf[t] = lf[t];
    __syncthreads();
    int cell = blockIdx.x * blockDim.x + t;          // (l,b) pair, 1800 total
    if (cell < N_L * N_B) {
        float acc[N_OUTK];
        #pragma unroll
        for (int k = 0; k < N_OUTK; ++k) acc[k] = 0.0f;
        #pragma unroll 2
        for (int i = 0; i < N_MU; ++i) {
            float h = hist[cell * N_MU + i];
            #pragma unroll
            for (int k = 0; k < N_OUTK; ++k)
                acc[k] += h * s_lf[k + (N_MU - 1) - i];
        }
        #pragma unroll
        for (int k = 0; k < N_OUTK; ++k)
            out[cell * N_OUTK + k] = acc[k];
    }
}

// ---------------- launch ----------------------------------------------------

extern "C" void kernel_launch(void* const* d_in, const int* in_sizes, int n_in,
                              void* d_out, int out_size, void* d_ws, size_t ws_size,
                              hipStream_t stream) {
    const float4* lbm4 = (const float4*)d_in[0];   // [20e6, 3] f32
    const float4* m4   = (const float4*)d_in[1];   // [20e6]    f32
    const float*  lf   = (const float*)d_in[2];    // [51]      f32
    float* out = (float*)d_out;                    // [90,20,6] f32

    // ws budget: R*C slices of SLICE floats + final hist of N_CELLS floats.
    size_t ws_floats = ws_size / sizeof(float);
    long long avail = (long long)ws_floats - N_CELLS;
    int C = 0;
    if (avail > 0) C = (int)(avail / ((long long)R_SPLIT * SLICE));
    if (C > C_MAX) C = C_MAX;

    if (C >= 8) {
        float* slices = (float*)d_ws;
        float* hist   = slices + (size_t)R_SPLIT * C * SLICE;
        int quads_per_chunk = (QUADS + C - 1) / C;
        hist_lds_kernel<<<C * R_SPLIT, HIST_BLOCK, 0, stream>>>(
            lbm4, m4, slices, C, quads_per_chunk);
        reduce_kernel<<<(N_CELLS + 255) / 256, 256, 0, stream>>>(slices, hist, C);
        conv_kernel<<<(N_L * N_B + 255) / 256, 256, 0, stream>>>(hist, lf, out);
    } else {
        // ws too small for privatized copies: round-1 global-atomic path
        float* hist = (float*)d_ws;                // 331 KB, known to fit
        zero_hist_kernel<<<(N_CELLS + 255) / 256, 256, 0, stream>>>(hist);
        hist_atomic_kernel<<<(QUADS + 255) / 256, 256, 0, stream>>>(lbm4, m4, hist);
        conv_kernel<<<(N_L * N_B + 255) / 256, 256, 0, stream>>>(hist, lf, out);
    }
}